// Round 2
// baseline (519.813 us; speedup 1.0000x reference)
//
#include <hip/hip_runtime.h>
#include <hip/hip_bf16.h>

#define S_LEN 2048
#define DMODEL 1024
#define DHEAD 64
#define NBATCH 4

// ws layout (float offsets)
#define QOFF   0
#define KOFF   (NBATCH*S_LEN*DHEAD)           // 524288
#define VOFF   (2*NBATCH*S_LEN*DHEAD)         // 1048576
#define WTOFF  (3*NBATCH*S_LEN*DHEAD)         // 1572864  (3 x [64][1024])
#define POFF   (WTOFF + 3*DMODEL*DHEAD)       // 1769472  (1024 slots x 64x64)
#define NSLOTS (NBATCH*32*8)                  // 1024
#define PMOFF  (POFF + NSLOTS*64*64)          // 5963776
#define PLOFF  (PMOFF + NSLOTS*64)            // 6029312
// total ws use: 6094848 floats = 23.3 MiB

// quad-granularity XOR swizzle: bank-floor ds_read_b128 for row-slice and
// column-slice access patterns (row>>4 term spreads the stride-4-row reads).
__device__ __forceinline__ int swq(int row, int c4) {
    return (c4 ^ (row & 15) ^ (row >> 4)) & 15;
}
__device__ __forceinline__ float4 lds_ld4(const float* buf, int row, int c4) {
    return *reinterpret_cast<const float4*>(buf + (row << 6) + (swq(row, c4) << 2));
}
__device__ __forceinline__ void lds_st4(float* buf, int row, int c4, float4 v) {
    *reinterpret_cast<float4*>(buf + (row << 6) + (swq(row, c4) << 2)) = v;
}

// stage a 64x64 f32 tile from global (leading dim ld) into swizzled LDS
__device__ __forceinline__ void stage_tile(float* dst, const float* __restrict__ src,
                                           int ld, int t, float scale) {
    const int c4 = t & 15;
    const int r0 = t >> 4;
    #pragma unroll
    for (int rep = 0; rep < 4; ++rep) {
        const int row = rep * 16 + r0;
        float4 v = *reinterpret_cast<const float4*>(src + (size_t)row * ld + (c4 << 2));
        v.x *= scale; v.y *= scale; v.z *= scale; v.w *= scale;
        lds_st4(dst, row, c4, v);
    }
}

// ---------------- W transpose: W[1024][64] -> Wt[64][1024] ----------------
__global__ __launch_bounds__(256) void wt_kernel(const float* __restrict__ WQ,
                                                 const float* __restrict__ WK,
                                                 const float* __restrict__ WV,
                                                 float* __restrict__ ws) {
    const int p = blockIdx.y;
    const float* W = (p == 0) ? WQ : (p == 1) ? WK : WV;
    const int idx = blockIdx.x * 256 + threadIdx.x;    // 0..65535
    const int n = idx & 63;
    const int d = idx >> 6;
    ws[WTOFF + (size_t)p * DMODEL * DHEAD + (size_t)n * DMODEL + d] = W[(size_t)d * DHEAD + n];
}

// ---------------- projections: out = X @ W  (M=8192, K=1024, N=64) --------
__global__ __launch_bounds__(256) void proj_kernel(const float* __restrict__ Q,
                                                   const float* __restrict__ K,
                                                   const float* __restrict__ V,
                                                   float* __restrict__ ws) {
    const int p = blockIdx.y;
    const float* X = (p == 0) ? Q : (p == 1) ? K : V;
    const float* W = ws + WTOFF + (size_t)p * DMODEL * DHEAD;   // [64][1024]
    float* out = ws + (size_t)p * (NBATCH * S_LEN * DHEAD);
    const int rt = blockIdx.x;                                  // 0..127
    __shared__ float xl[4096];
    __shared__ float wl[4096];
    const int t = threadIdx.x;
    const int rg = t >> 4, cg = t & 15;
    float acc[4][4] = {};
    for (int ch = 0; ch < DMODEL / 64; ++ch) {
        __syncthreads();
        stage_tile(xl, X + (size_t)rt * 64 * DMODEL + ch * 64, DMODEL, t, 1.0f);
        stage_tile(wl, W + ch * 64, DMODEL, t, 1.0f);
        __syncthreads();
        #pragma unroll
        for (int k4 = 0; k4 < 16; ++k4) {
            float4 xv[4], wv[4];
            #pragma unroll
            for (int i = 0; i < 4; ++i) xv[i] = lds_ld4(xl, rg * 4 + i, k4);
            #pragma unroll
            for (int j = 0; j < 4; ++j) wv[j] = lds_ld4(wl, cg * 4 + j, k4);
            #pragma unroll
            for (int i = 0; i < 4; ++i)
                #pragma unroll
                for (int j = 0; j < 4; ++j)
                    acc[i][j] += xv[i].x * wv[j].x + xv[i].y * wv[j].y
                               + xv[i].z * wv[j].z + xv[i].w * wv[j].w;
        }
    }
    #pragma unroll
    for (int i = 0; i < 4; ++i) {
        float4 o = make_float4(acc[i][0], acc[i][1], acc[i][2], acc[i][3]);
        *reinterpret_cast<float4*>(out + (size_t)(rt * 64 + rg * 4 + i) * DHEAD + cg * 4) = o;
    }
}

// ---------------- flash attention, causal, kv-chunked ----------------------
__global__ __launch_bounds__(256) void attn_kernel(float* __restrict__ ws) {
    const int chunk = blockIdx.x;            // 0..7
    const int qt = 31 - blockIdx.y;          // reversed: long tasks dispatch first
    const int b = blockIdx.z;
    const int Li = qt + 1;                   // causal kv-tile count for this q-tile
    const int kt0 = chunk * 4;
    if (kt0 >= Li) return;
    const int kt1 = (kt0 + 4 < Li) ? kt0 + 4 : Li;
    const float* q = ws + QOFF + (size_t)b * S_LEN * DHEAD;
    const float* k = ws + KOFF + (size_t)b * S_LEN * DHEAD;
    const float* v = ws + VOFF + (size_t)b * S_LEN * DHEAD;
    __shared__ float ql[4096];
    __shared__ float kl[4096];   // reused as P-tile after scores are consumed
    __shared__ float vl[4096];
    const int t = threadIdx.x;
    const int rg = t >> 4, cg = t & 15;
    stage_tile(ql, q + (size_t)qt * 64 * DHEAD, DHEAD, t, 0.125f);  // 1/sqrt(64)
    float m[4], l[4], o[4][4] = {};
    #pragma unroll
    for (int i = 0; i < 4; ++i) { m[i] = -1e30f; l[i] = 0.0f; }
    for (int kt = kt0; kt < kt1; ++kt) {
        __syncthreads();   // prev PV done (kl/vl free); ql staged on first iter
        stage_tile(kl, k + (size_t)kt * 64 * DHEAD, DHEAD, t, 1.0f);
        stage_tile(vl, v + (size_t)kt * 64 * DHEAD, DHEAD, t, 1.0f);
        __syncthreads();
        float s[4][4] = {};
        #pragma unroll
        for (int k4 = 0; k4 < 16; ++k4) {
            float4 qv[4], kv[4];
            #pragma unroll
            for (int i = 0; i < 4; ++i) qv[i] = lds_ld4(ql, rg * 4 + i, k4);
            #pragma unroll
            for (int j = 0; j < 4; ++j) kv[j] = lds_ld4(kl, cg * 4 + j, k4);
            #pragma unroll
            for (int i = 0; i < 4; ++i)
                #pragma unroll
                for (int j = 0; j < 4; ++j)
                    s[i][j] += qv[i].x * kv[j].x + qv[i].y * kv[j].y
                             + qv[i].z * kv[j].z + qv[i].w * kv[j].w;
        }
        if (kt == qt) {    // diagonal tile: causal mask
            #pragma unroll
            for (int i = 0; i < 4; ++i)
                #pragma unroll
                for (int j = 0; j < 4; ++j)
                    if (cg * 4 + j > rg * 4 + i) s[i][j] = -1e30f;
        }
        float p[4][4];
        #pragma unroll
        for (int i = 0; i < 4; ++i) {
            float mx = fmaxf(fmaxf(s[i][0], s[i][1]), fmaxf(s[i][2], s[i][3]));
            #pragma unroll
            for (int off = 1; off < 16; off <<= 1)
                mx = fmaxf(mx, __shfl_xor(mx, off));
            const float nm = fmaxf(m[i], mx);
            const float sc = __expf(m[i] - nm);
            m[i] = nm;
            float rs = 0.0f;
            #pragma unroll
            for (int j = 0; j < 4; ++j) { p[i][j] = __expf(s[i][j] - nm); rs += p[i][j]; }
            #pragma unroll
            for (int off = 1; off < 16; off <<= 1)
                rs += __shfl_xor(rs, off);
            l[i] = l[i] * sc + rs;
            #pragma unroll
            for (int j = 0; j < 4; ++j) o[i][j] *= sc;
        }
        __syncthreads();   // all reads of kl (scores) done -> safe to overwrite
        #pragma unroll
        for (int i = 0; i < 4; ++i)
            lds_st4(kl, rg * 4 + i, cg, make_float4(p[i][0], p[i][1], p[i][2], p[i][3]));
        __syncthreads();   // P visible
        #pragma unroll
        for (int c4 = 0; c4 < 16; ++c4) {
            float4 pv[4], vv[4];
            #pragma unroll
            for (int i = 0; i < 4; ++i) pv[i] = lds_ld4(kl, rg * 4 + i, c4);
            #pragma unroll
            for (int cc = 0; cc < 4; ++cc) vv[cc] = lds_ld4(vl, c4 * 4 + cc, cg);
            #pragma unroll
            for (int i = 0; i < 4; ++i) {
                o[i][0] += pv[i].x*vv[0].x + pv[i].y*vv[1].x + pv[i].z*vv[2].x + pv[i].w*vv[3].x;
                o[i][1] += pv[i].x*vv[0].y + pv[i].y*vv[1].y + pv[i].z*vv[2].y + pv[i].w*vv[3].y;
                o[i][2] += pv[i].x*vv[0].z + pv[i].y*vv[1].z + pv[i].z*vv[2].z + pv[i].w*vv[3].z;
                o[i][3] += pv[i].x*vv[0].w + pv[i].y*vv[1].w + pv[i].z*vv[2].w + pv[i].w*vv[3].w;
            }
        }
    }
    const int slot = (b * 32 + qt) * 8 + chunk;
    float* Op = ws + POFF + (size_t)slot * 4096;
    #pragma unroll
    for (int i = 0; i < 4; ++i)
        *reinterpret_cast<float4*>(Op + (size_t)(rg * 4 + i) * 64 + cg * 4) =
            make_float4(o[i][0], o[i][1], o[i][2], o[i][3]);
    if (cg == 0) {
        #pragma unroll
        for (int i = 0; i < 4; ++i) {
            ws[PMOFF + (size_t)slot * 64 + rg * 4 + i] = m[i];
            ws[PLOFF + (size_t)slot * 64 + rg * 4 + i] = l[i];
        }
    }
}

// ---------------- merge partials -> final output ---------------------------
__global__ __launch_bounds__(256) void merge_kernel(const float* __restrict__ ws,
                                                    float* __restrict__ out) {
    const int qt = blockIdx.x;               // 0..31
    const int b = blockIdx.y;                // 0..3
    const int Ci = qt / 4 + 1;               // valid chunks
    const int t = threadIdx.x;
    const int d = t & 63;
    const int rgrp = t >> 6;                 // 0..3
    const int slot0 = (b * 32 + qt) * 8;
    for (int rr = 0; rr < 16; ++rr) {
        const int row = rgrp + rr * 4;
        float M = -1e30f;
        for (int c = 0; c < Ci; ++c)
            M = fmaxf(M, ws[PMOFF + (size_t)(slot0 + c) * 64 + row]);
        float denom = 0.0f, acc = 0.0f;
        for (int c = 0; c < Ci; ++c) {
            const float w = __expf(ws[PMOFF + (size_t)(slot0 + c) * 64 + row] - M);
            denom += w * ws[PLOFF + (size_t)(slot0 + c) * 64 + row];
            acc   += w * ws[POFF + (size_t)(slot0 + c) * 4096 + (size_t)row * 64 + d];
        }
        out[(size_t)((b * 32 + qt) * 64 + row) * 64 + d] = acc / denom;
    }
}

extern "C" void kernel_launch(void* const* d_in, const int* in_sizes, int n_in,
                              void* d_out, int out_size, void* d_ws, size_t ws_size,
                              hipStream_t stream) {
    (void)in_sizes; (void)n_in; (void)out_size; (void)ws_size;
    const float* Q  = (const float*)d_in[0];
    const float* K  = (const float*)d_in[1];
    const float* V  = (const float*)d_in[2];
    const float* WQ = (const float*)d_in[3];
    const float* WK = (const float*)d_in[4];
    const float* WV = (const float*)d_in[5];
    // d_in[6] (mask) is exactly tril ones -> causal handled analytically
    float* ws  = (float*)d_ws;
    float* out = (float*)d_out;

    wt_kernel<<<dim3(256, 3), dim3(256), 0, stream>>>(WQ, WK, WV, ws);
    proj_kernel<<<dim3(128, 3), dim3(256), 0, stream>>>(Q, K, V, ws);
    attn_kernel<<<dim3(8, 32, 4), dim3(256), 0, stream>>>(ws);
    merge_kernel<<<dim3(32, 4), dim3(256), 0, stream>>>(ws, out);
}

// Round 5
// 237.828 us; speedup vs baseline: 2.1857x; 2.1857x over previous
//
#include <hip/hip_runtime.h>

typedef unsigned int u32;
typedef unsigned short u16;
using bf16x8 = __attribute__((ext_vector_type(8))) short;
using f32x4  = __attribute__((ext_vector_type(4))) float;

#define MFMA16 __builtin_amdgcn_mfma_f32_16x16x32_bf16

// ---- ws byte offsets (total ~18.3 MiB) ----
#define QH  (0u)
#define QL  (1u<<20)
#define KHO (2u<<20)
#define KLO (3u<<20)
#define VHO (4u<<20)
#define VLO (5u<<20)
#define VTH (6u<<20)
#define VTL (7u<<20)
#define WTH (8u<<20)
#define WTL (WTH + 3u*64*1024*2)
#define OPOFF (9u<<20)
#define PMOFF (OPOFF + 576u*4096*4)
#define PLOFF (PMOFF + 576u*64*4)

__device__ __forceinline__ u16 f2bf(float x) {
    u32 u = __float_as_uint(x);
    return (u16)((u + 0x7FFFu + ((u >> 16) & 1u)) >> 16);
}
__device__ __forceinline__ float bf2f(u16 h) {
    return __uint_as_float(((u32)h) << 16);
}

// XOR swizzle: 16B chunk c (0..7) within a 128B row
__device__ __forceinline__ int swz(int row, int c) {
    return c ^ ((row ^ (row >> 3)) & 7);
}
__device__ __forceinline__ bf16x8 ldsf(const char* t, int row, int c) {
    return *reinterpret_cast<const bf16x8*>(t + row * 128 + swz(row, c) * 16);
}
__device__ __forceinline__ void ldst(char* t, int row, int c, bf16x8 v) {
    *reinterpret_cast<bf16x8*>(t + row * 128 + swz(row, c) * 16) = v;
}

// stage a 64x64 bf16 tile from global (row stride ldu elements) into swizzled LDS
__device__ __forceinline__ void stage_bf16(char* tile, const u16* g, int ldu, int t) {
    const int row = t >> 2, cg = t & 3;
    const char* gp = reinterpret_cast<const char*>(g + (size_t)row * ldu + cg * 16);
    bf16x8 a = *reinterpret_cast<const bf16x8*>(gp);
    bf16x8 b = *reinterpret_cast<const bf16x8*>(gp + 16);
    ldst(tile, row, cg * 2, a);
    ldst(tile, row, cg * 2 + 1, b);
}

// stage a 64x64 fp32 tile from global, split into hi/lo bf16 swizzled LDS tiles
__device__ __forceinline__ void stage_split(char* th, char* tl, const float* g, int ld, int t) {
    const int row = t >> 2, cg = t & 3;
    const float* gp = g + (size_t)row * ld + cg * 16;
    #pragma unroll
    for (int c = 0; c < 2; ++c) {
        bf16x8 h, l;
        #pragma unroll
        for (int j = 0; j < 8; ++j) {
            float x = gp[c * 8 + j];
            u16 hb = f2bf(x);
            u16 lb = f2bf(x - bf2f(hb));
            h[j] = (short)hb; l[j] = (short)lb;
        }
        ldst(th, row, cg * 2 + c, h);
        ldst(tl, row, cg * 2 + c, l);
    }
}

// ---------------- W prep: W[1024][64] fp32 -> Wt_hi/lo[64][1024] bf16 ----------
__global__ __launch_bounds__(256) void wsplit_kernel(const float* __restrict__ WQ,
                                                     const float* __restrict__ WK,
                                                     const float* __restrict__ WV,
                                                     char* __restrict__ ws) {
    const int p = blockIdx.y, kt = blockIdx.x;          // kt: 0..15
    const float* W = (p == 0) ? WQ : (p == 1) ? WK : WV;
    __shared__ float lds[64 * 68];
    const int t = threadIdx.x, row = t >> 2, cg = t & 3;
    const float* gp = W + ((size_t)kt * 64 + row) * 64 + cg * 16;
    #pragma unroll
    for (int j = 0; j < 16; ++j) lds[row * 68 + cg * 16 + j] = gp[j];
    __syncthreads();
    const int n = row, d0 = cg * 16;
    u32 wh[8], wl[8];
    #pragma unroll
    for (int j = 0; j < 8; ++j) {
        float x0 = lds[(d0 + 2 * j) * 68 + n];
        float x1 = lds[(d0 + 2 * j + 1) * 68 + n];
        u16 h0 = f2bf(x0), h1 = f2bf(x1);
        u16 l0 = f2bf(x0 - bf2f(h0)), l1 = f2bf(x1 - bf2f(h1));
        wh[j] = (u32)h0 | ((u32)h1 << 16);
        wl[j] = (u32)l0 | ((u32)l1 << 16);
    }
    u16* oh = (u16*)(ws + WTH) + (size_t)p * 64 * 1024 + (size_t)n * 1024 + kt * 64 + d0;
    u16* ol = (u16*)(ws + WTL) + (size_t)p * 64 * 1024 + (size_t)n * 1024 + kt * 64 + d0;
    uint4 a = {wh[0], wh[1], wh[2], wh[3]}, b = {wh[4], wh[5], wh[6], wh[7]};
    uint4 c = {wl[0], wl[1], wl[2], wl[3]}, d = {wl[4], wl[5], wl[6], wl[7]};
    *reinterpret_cast<uint4*>(oh) = a; *reinterpret_cast<uint4*>(oh + 8) = b;
    *reinterpret_cast<uint4*>(ol) = c; *reinterpret_cast<uint4*>(ol + 8) = d;
}

// ---------------- projections: split-bf16 MFMA, out = X @ W -------------------
__global__ __launch_bounds__(256) void proj_kernel(const float* __restrict__ Q,
                                                   const float* __restrict__ K,
                                                   const float* __restrict__ V,
                                                   char* __restrict__ ws) {
    const int p = blockIdx.y;
    const float* X = (p == 0) ? Q : (p == 1) ? K : V;
    const u16* wth = (const u16*)(ws + WTH) + (size_t)p * 64 * 1024;
    const u16* wtl = (const u16*)(ws + WTL) + (size_t)p * 64 * 1024;
    u16* oh = (u16*)(ws + ((p == 0) ? QH : (p == 1) ? KHO : VHO));
    u16* ol = (u16*)(ws + ((p == 0) ? QL : (p == 1) ? KLO : VLO));
    const int rt = blockIdx.x;                          // 0..127
    __shared__ char xh[8192], xl[8192], bh_[8192], bl_[8192];
    const int t = threadIdx.x, lane = t & 63, w = t >> 6;
    f32x4 acc[4];
    #pragma unroll
    for (int nt = 0; nt < 4; ++nt) acc[nt] = (f32x4){0.f, 0.f, 0.f, 0.f};
    for (int kc = 0; kc < 1024; kc += 64) {
        __syncthreads();
        stage_split(xh, xl, X + (size_t)rt * 64 * 1024 + kc, 1024, t);
        stage_bf16(bh_, wth + kc, 1024, t);
        stage_bf16(bl_, wtl + kc, 1024, t);
        __syncthreads();
        #pragma unroll
        for (int s = 0; s < 2; ++s) {
            bf16x8 ah = ldsf(xh, w * 16 + (lane & 15), s * 4 + (lane >> 4));
            bf16x8 al = ldsf(xl, w * 16 + (lane & 15), s * 4 + (lane >> 4));
            #pragma unroll
            for (int nt = 0; nt < 4; ++nt) {
                bf16x8 bh = ldsf(bh_, nt * 16 + (lane & 15), s * 4 + (lane >> 4));
                bf16x8 bl = ldsf(bl_, nt * 16 + (lane & 15), s * 4 + (lane >> 4));
                acc[nt] = MFMA16(ah, bh, acc[nt], 0, 0, 0);
                acc[nt] = MFMA16(ah, bl, acc[nt], 0, 0, 0);
                acc[nt] = MFMA16(al, bh, acc[nt], 0, 0, 0);
            }
        }
    }
    const float qs = (p == 0) ? 0.125f : 1.0f;          // fold 1/sqrt(64) into q
    #pragma unroll
    for (int nt = 0; nt < 4; ++nt)
        #pragma unroll
        for (int r = 0; r < 4; ++r) {
            float v = acc[nt][r] * qs;
            u16 hb = f2bf(v);
            u16 lb = f2bf(v - bf2f(hb));
            size_t idx = ((size_t)rt * 64 + w * 16 + (lane >> 4) * 4 + r) * 64 + nt * 16 + (lane & 15);
            oh[idx] = hb; ol[idx] = lb;
        }
}

// ---------------- V transpose: v[b][2048][64] -> vT[b][64][2048] (bf16 hi/lo) --
__global__ __launch_bounds__(256) void vt_kernel(char* __restrict__ ws) {
    const int st = blockIdx.x, b = blockIdx.y;          // st: 0..31
    __shared__ u16 lh[64 * 72], ll[64 * 72];
    const int t = threadIdx.x, row = t >> 2, cg = t & 3;
    const u16* vh = (const u16*)(ws + VHO) + ((size_t)b * 2048 + st * 64 + row) * 64 + cg * 16;
    const u16* vl = (const u16*)(ws + VLO) + ((size_t)b * 2048 + st * 64 + row) * 64 + cg * 16;
    *reinterpret_cast<uint4*>(&lh[row * 72 + cg * 16]) = *reinterpret_cast<const uint4*>(vh);
    *reinterpret_cast<uint4*>(&lh[row * 72 + cg * 16 + 8]) = *reinterpret_cast<const uint4*>(vh + 8);
    *reinterpret_cast<uint4*>(&ll[row * 72 + cg * 16]) = *reinterpret_cast<const uint4*>(vl);
    *reinterpret_cast<uint4*>(&ll[row * 72 + cg * 16 + 8]) = *reinterpret_cast<const uint4*>(vl + 8);
    __syncthreads();
    const int d = row, s0 = cg * 16;
    u32 wh[8], wl[8];
    #pragma unroll
    for (int j = 0; j < 8; ++j) {
        wh[j] = (u32)lh[(s0 + 2 * j) * 72 + d] | ((u32)lh[(s0 + 2 * j + 1) * 72 + d] << 16);
        wl[j] = (u32)ll[(s0 + 2 * j) * 72 + d] | ((u32)ll[(s0 + 2 * j + 1) * 72 + d] << 16);
    }
    u16* th = (u16*)(ws + VTH) + ((size_t)b * 64 + d) * 2048 + st * 64 + s0;
    u16* tl = (u16*)(ws + VTL) + ((size_t)b * 64 + d) * 2048 + st * 64 + s0;
    uint4 a = {wh[0], wh[1], wh[2], wh[3]}, bb = {wh[4], wh[5], wh[6], wh[7]};
    uint4 c = {wl[0], wl[1], wl[2], wl[3]}, dd = {wl[4], wl[5], wl[6], wl[7]};
    *reinterpret_cast<uint4*>(th) = a; *reinterpret_cast<uint4*>(th + 8) = bb;
    *reinterpret_cast<uint4*>(tl) = c; *reinterpret_cast<uint4*>(tl + 8) = dd;
}

// packed causal-chunk slot base: sum over j<qt of (j/4+1)
__device__ __forceinline__ int slot_base(int qt) {
    const int q4 = qt >> 2, r = qt & 3;
    return qt + 2 * q4 * (q4 - 1) + r * q4;
}

// ---------------- flash attention: split-bf16 MFMA, causal, kv-chunked --------
__global__ __launch_bounds__(256) void attn_kernel(char* __restrict__ ws) {
    const int chunk = blockIdx.x;            // 0..7
    const int qt = 31 - blockIdx.y;
    const int b = blockIdx.z;
    const int Li = qt + 1, kt0 = chunk * 4;
    if (kt0 >= Li) return;
    const int kt1 = (kt0 + 4 < Li) ? kt0 + 4 : Li;
    __shared__ char kh[8192], kl[8192], vh[8192], vl[8192], ph[8192], pl[8192];
    const int t = threadIdx.x, lane = t & 63, w = t >> 6;
    // Q fragments straight from global (hi/lo), once
    const u16* qhg = (const u16*)(ws + QH);
    const u16* qlg = (const u16*)(ws + QL);
    const size_t qrow = (size_t)b * 2048 + qt * 64 + w * 16 + (lane & 15);
    bf16x8 qfh[2], qfl[2];
    #pragma unroll
    for (int s = 0; s < 2; ++s) {
        qfh[s] = *reinterpret_cast<const bf16x8*>(qhg + qrow * 64 + s * 32 + (lane >> 4) * 8);
        qfl[s] = *reinterpret_cast<const bf16x8*>(qlg + qrow * 64 + s * 32 + (lane >> 4) * 8);
    }
    const u16* kgh = (const u16*)(ws + KHO) + (size_t)b * 2048 * 64;
    const u16* kgl = (const u16*)(ws + KLO) + (size_t)b * 2048 * 64;
    const u16* vgh = (const u16*)(ws + VTH) + (size_t)b * 64 * 2048;
    const u16* vgl = (const u16*)(ws + VTL) + (size_t)b * 64 * 2048;
    f32x4 o[4];
    #pragma unroll
    for (int nt = 0; nt < 4; ++nt) o[nt] = (f32x4){0.f, 0.f, 0.f, 0.f};
    float mrow[4], lrow[4];
    #pragma unroll
    for (int r = 0; r < 4; ++r) { mrow[r] = -1e30f; lrow[r] = 0.f; }
    for (int kt = kt0; kt < kt1; ++kt) {
        __syncthreads();
        stage_bf16(kh, kgh + (size_t)kt * 64 * 64, 64, t);
        stage_bf16(kl, kgl + (size_t)kt * 64 * 64, 64, t);
        stage_bf16(vh, vgh + kt * 64, 2048, t);
        stage_bf16(vl, vgl + kt * 64, 2048, t);
        __syncthreads();
        f32x4 sacc[4];
        #pragma unroll
        for (int nt = 0; nt < 4; ++nt) sacc[nt] = (f32x4){0.f, 0.f, 0.f, 0.f};
        #pragma unroll
        for (int s = 0; s < 2; ++s) {
            #pragma unroll
            for (int nt = 0; nt < 4; ++nt) {
                bf16x8 bh = ldsf(kh, nt * 16 + (lane & 15), s * 4 + (lane >> 4));
                bf16x8 bl = ldsf(kl, nt * 16 + (lane & 15), s * 4 + (lane >> 4));
                sacc[nt] = MFMA16(qfh[s], bh, sacc[nt], 0, 0, 0);
                sacc[nt] = MFMA16(qfh[s], bl, sacc[nt], 0, 0, 0);
                sacc[nt] = MFMA16(qfl[s], bh, sacc[nt], 0, 0, 0);
            }
        }
        if (kt == qt) {   // diagonal tile causal mask (tile-local compare)
            #pragma unroll
            for (int nt = 0; nt < 4; ++nt)
                #pragma unroll
                for (int r = 0; r < 4; ++r)
                    if (nt * 16 + (lane & 15) > w * 16 + (lane >> 4) * 4 + r)
                        sacc[nt][r] = -1e30f;
        }
        // online softmax (rows r across regs; cols across 16-lane groups)
        float pcur[4][4], scv[4];
        #pragma unroll
        for (int r = 0; r < 4; ++r) {
            float mx = fmaxf(fmaxf(sacc[0][r], sacc[1][r]), fmaxf(sacc[2][r], sacc[3][r]));
            #pragma unroll
            for (int off = 1; off < 16; off <<= 1) mx = fmaxf(mx, __shfl_xor(mx, off));
            const float nm = fmaxf(mrow[r], mx);
            scv[r] = __expf(mrow[r] - nm);
            mrow[r] = nm;
            float rs = 0.f;
            #pragma unroll
            for (int nt = 0; nt < 4; ++nt) {
                float pv = __expf(sacc[nt][r] - nm);
                pcur[nt][r] = pv; rs += pv;
            }
            #pragma unroll
            for (int off = 1; off < 16; off <<= 1) rs += __shfl_xor(rs, off);
            lrow[r] = lrow[r] * scv[r] + rs;
        }
        f32x4 scq = {scv[0], scv[1], scv[2], scv[3]};
        #pragma unroll
        for (int nt = 0; nt < 4; ++nt) o[nt] *= scq;
        // split P and write to per-wave LDS region (rows w*16..w*16+15)
        #pragma unroll
        for (int nt = 0; nt < 4; ++nt)
            #pragma unroll
            for (int r = 0; r < 4; ++r) {
                const int row = w * 16 + (lane >> 4) * 4 + r;
                const int key = nt * 16 + (lane & 15);
                u16 hb = f2bf(pcur[nt][r]);
                u16 lb = f2bf(pcur[nt][r] - bf2f(hb));
                const int byt = row * 128 + swz(row, key >> 3) * 16 + (key & 7) * 2;
                *reinterpret_cast<u16*>(ph + byt) = hb;
                *reinterpret_cast<u16*>(pl + byt) = lb;
            }
        // PV (wave-local P readback; compiler orders same-wave ds ops)
        #pragma unroll
        for (int s = 0; s < 2; ++s) {
            bf16x8 pah = ldsf(ph, w * 16 + (lane & 15), s * 4 + (lane >> 4));
            bf16x8 pal = ldsf(pl, w * 16 + (lane & 15), s * 4 + (lane >> 4));
            #pragma unroll
            for (int nt = 0; nt < 4; ++nt) {
                bf16x8 vbh = ldsf(vh, nt * 16 + (lane & 15), s * 4 + (lane >> 4));
                bf16x8 vbl = ldsf(vl, nt * 16 + (lane & 15), s * 4 + (lane >> 4));
                o[nt] = MFMA16(pah, vbh, o[nt], 0, 0, 0);
                o[nt] = MFMA16(pah, vbl, o[nt], 0, 0, 0);
                o[nt] = MFMA16(pal, vbh, o[nt], 0, 0, 0);
            }
        }
    }
    const int slot = b * 144 + slot_base(qt) + chunk;
    float* Op = (float*)(ws + OPOFF) + (size_t)slot * 4096;
    #pragma unroll
    for (int nt = 0; nt < 4; ++nt)
        #pragma unroll
        for (int r = 0; r < 4; ++r)
            Op[(size_t)(w * 16 + (lane >> 4) * 4 + r) * 64 + nt * 16 + (lane & 15)] = o[nt][r];
    if ((lane & 15) == 0) {
        float* Pm = (float*)(ws + PMOFF);
        float* Pl = (float*)(ws + PLOFF);
        #pragma unroll
        for (int r = 0; r < 4; ++r) {
            Pm[(size_t)slot * 64 + w * 16 + (lane >> 4) * 4 + r] = mrow[r];
            Pl[(size_t)slot * 64 + w * 16 + (lane >> 4) * 4 + r] = lrow[r];
        }
    }
}

// ---------------- merge partials -> final output ------------------------------
__global__ __launch_bounds__(256) void merge_kernel(const char* __restrict__ ws,
                                                    float* __restrict__ out) {
    const int qt = blockIdx.x, b = blockIdx.y;
    const int Ci = (qt >> 2) + 1;
    const int slot0 = b * 144 + slot_base(qt);
    const float* Op = (const float*)(ws + OPOFF);
    const float* Pm = (const float*)(ws + PMOFF);
    const float* Pl = (const float*)(ws + PLOFF);
    const int t = threadIdx.x, d = t & 63, rg = t >> 6;
    for (int rv = 0; rv < 16; ++rv) {
        const int row = rg + rv * 4;
        float M = -1e30f;
        for (int c = 0; c < Ci; ++c) M = fmaxf(M, Pm[(size_t)(slot0 + c) * 64 + row]);
        float den = 0.f, acc = 0.f;
        for (int c = 0; c < Ci; ++c) {
            const float wv = __expf(Pm[(size_t)(slot0 + c) * 64 + row] - M);
            den += wv * Pl[(size_t)(slot0 + c) * 64 + row];
            acc += wv * Op[(size_t)(slot0 + c) * 4096 + (size_t)row * 64 + d];
        }
        out[(size_t)((b * 32 + qt) * 64 + row) * 64 + d] = acc / den;
    }
}

extern "C" void kernel_launch(void* const* d_in, const int* in_sizes, int n_in,
                              void* d_out, int out_size, void* d_ws, size_t ws_size,
                              hipStream_t stream) {
    (void)in_sizes; (void)n_in; (void)out_size; (void)ws_size;
    const float* Q  = (const float*)d_in[0];
    const float* K  = (const float*)d_in[1];
    const float* V  = (const float*)d_in[2];
    const float* WQ = (const float*)d_in[3];
    const float* WK = (const float*)d_in[4];
    const float* WV = (const float*)d_in[5];
    char* ws   = (char*)d_ws;
    float* out = (float*)d_out;

    wsplit_kernel<<<dim3(16, 3), dim3(256), 0, stream>>>(WQ, WK, WV, ws);
    proj_kernel<<<dim3(128, 3), dim3(256), 0, stream>>>(Q, K, V, ws);
    vt_kernel<<<dim3(32, 4), dim3(256), 0, stream>>>(ws);
    attn_kernel<<<dim3(8, 32, 4), dim3(256), 0, stream>>>(ws);
    merge_kernel<<<dim3(32, 4), dim3(256), 0, stream>>>(ws, out);
}

// Round 8
// 191.403 us; speedup vs baseline: 2.7158x; 1.2425x over previous
//
#include <hip/hip_runtime.h>

typedef unsigned int u32;
typedef unsigned short u16;
using bf16x8 = __attribute__((ext_vector_type(8))) short;
using f32x4  = __attribute__((ext_vector_type(4))) float;

#define MFMA16 __builtin_amdgcn_mfma_f32_16x16x32_bf16

// ---- ws byte offsets (total ~18.3 MiB) ----
#define QH  (0u)
#define QL  (1u<<20)
#define KHO (2u<<20)
#define KLO (3u<<20)
#define VHO (4u<<20)
#define VLO (5u<<20)
#define VTH (6u<<20)
#define VTL (7u<<20)
#define WTH (8u<<20)
#define WTL (WTH + 3u*64*1024*2)
#define OPOFF (9u<<20)
#define PMOFF (OPOFF + 576u*4096*4)
#define PLOFF (PMOFF + 576u*64*4)

__device__ __forceinline__ u16 f2bf(float x) {
    u32 u = __float_as_uint(x);
    return (u16)((u + 0x7FFFu + ((u >> 16) & 1u)) >> 16);
}
__device__ __forceinline__ float bf2f(u16 h) {
    return __uint_as_float(((u32)h) << 16);
}

// XOR swizzle: 16B chunk c (0..7) within a 128B row
__device__ __forceinline__ int swz(int row, int c) {
    return c ^ ((row ^ (row >> 3)) & 7);
}
__device__ __forceinline__ bf16x8 ldsf(const char* t, int row, int c) {
    return *reinterpret_cast<const bf16x8*>(t + row * 128 + swz(row, c) * 16);
}
__device__ __forceinline__ void ldst(char* t, int row, int c, bf16x8 v) {
    *reinterpret_cast<bf16x8*>(t + row * 128 + swz(row, c) * 16) = v;
}

// split 8 fp32 (two float4) into hi/lo bf16x8
__device__ __forceinline__ void split8(float4 v0, float4 v1, bf16x8& h, bf16x8& l) {
    float e[8] = {v0.x, v0.y, v0.z, v0.w, v1.x, v1.y, v1.z, v1.w};
    #pragma unroll
    for (int j = 0; j < 8; ++j) {
        u16 hb = f2bf(e[j]);
        h[j] = (short)hb;
        l[j] = (short)f2bf(e[j] - bf2f(hb));
    }
}

// ---------------- W prep: W[1024][64] fp32 -> Wt_hi/lo[64][1024] bf16 ----------
__global__ __launch_bounds__(256) void wsplit_kernel(const float* __restrict__ WQ,
                                                     const float* __restrict__ WK,
                                                     const float* __restrict__ WV,
                                                     char* __restrict__ ws) {
    const int p = blockIdx.y, kt = blockIdx.x;          // kt: 0..15
    const float* W = (p == 0) ? WQ : (p == 1) ? WK : WV;
    __shared__ float lds[64 * 68];
    const int t = threadIdx.x, row = t >> 2, cg = t & 3;
    const float* gp = W + ((size_t)kt * 64 + row) * 64 + cg * 16;
    #pragma unroll
    for (int j = 0; j < 16; ++j) lds[row * 68 + cg * 16 + j] = gp[j];
    __syncthreads();
    const int n = row, d0 = cg * 16;
    u32 wh[8], wl[8];
    #pragma unroll
    for (int j = 0; j < 8; ++j) {
        float x0 = lds[(d0 + 2 * j) * 68 + n];
        float x1 = lds[(d0 + 2 * j + 1) * 68 + n];
        u16 h0 = f2bf(x0), h1 = f2bf(x1);
        u16 l0 = f2bf(x0 - bf2f(h0)), l1 = f2bf(x1 - bf2f(h1));
        wh[j] = (u32)h0 | ((u32)h1 << 16);
        wl[j] = (u32)l0 | ((u32)l1 << 16);
    }
    u16* oh = (u16*)(ws + WTH) + (size_t)p * 64 * 1024 + (size_t)n * 1024 + kt * 64 + d0;
    u16* ol = (u16*)(ws + WTL) + (size_t)p * 64 * 1024 + (size_t)n * 1024 + kt * 64 + d0;
    uint4 a = {wh[0], wh[1], wh[2], wh[3]}, b = {wh[4], wh[5], wh[6], wh[7]};
    uint4 c = {wl[0], wl[1], wl[2], wl[3]}, d = {wl[4], wl[5], wl[6], wl[7]};
    *reinterpret_cast<uint4*>(oh) = a; *reinterpret_cast<uint4*>(oh + 8) = b;
    *reinterpret_cast<uint4*>(ol) = c; *reinterpret_cast<uint4*>(ol + 8) = d;
}

// ---------------- projections: split-bf16 MFMA + async-stage ------------------
__global__ __launch_bounds__(256) void proj_kernel(const float* __restrict__ Q,
                                                   const float* __restrict__ K,
                                                   const float* __restrict__ V,
                                                   char* __restrict__ ws) {
    const int p = blockIdx.y;
    const float* X = (p == 0) ? Q : (p == 1) ? K : V;
    const u16* wth = (const u16*)(ws + WTH) + (size_t)p * 64 * 1024;
    const u16* wtl = (const u16*)(ws + WTL) + (size_t)p * 64 * 1024;
    u16* oh = (u16*)(ws + ((p == 0) ? QH : (p == 1) ? KHO : VHO));
    u16* ol = (u16*)(ws + ((p == 0) ? QL : (p == 1) ? KLO : VLO));
    const int rt = blockIdx.x;                          // 0..127
    __shared__ char xh[8192], xl[8192], bh_[8192], bl_[8192];
    const int t = threadIdx.x, lane = t & 63, w = t >> 6;
    const int rs = t >> 2, cs = t & 3;

    auto ldrow = [&](int kc, float4* xr, bf16x8* wr) {
        const float* gp = X + (size_t)rt * 64 * 1024 + (size_t)rs * 1024 + kc + cs * 16;
        xr[0] = *reinterpret_cast<const float4*>(gp);
        xr[1] = *reinterpret_cast<const float4*>(gp + 4);
        xr[2] = *reinterpret_cast<const float4*>(gp + 8);
        xr[3] = *reinterpret_cast<const float4*>(gp + 12);
        const u16* ph_ = wth + (size_t)rs * 1024 + kc + cs * 16;
        const u16* pl_ = wtl + (size_t)rs * 1024 + kc + cs * 16;
        wr[0] = *reinterpret_cast<const bf16x8*>(ph_);
        wr[1] = *reinterpret_cast<const bf16x8*>(ph_ + 8);
        wr[2] = *reinterpret_cast<const bf16x8*>(pl_);
        wr[3] = *reinterpret_cast<const bf16x8*>(pl_ + 8);
    };

    f32x4 acc[4];
    #pragma unroll
    for (int nt = 0; nt < 4; ++nt) acc[nt] = (f32x4){0.f, 0.f, 0.f, 0.f};
    float4 xc[4], xn[4];
    bf16x8 wc[4], wn[4];
    ldrow(0, xc, wc);
    for (int kc = 0; kc < 1024; kc += 64) {
        __syncthreads();
        bf16x8 h0, l0, h1, l1;
        split8(xc[0], xc[1], h0, l0);
        split8(xc[2], xc[3], h1, l1);
        ldst(xh, rs, cs * 2, h0);     ldst(xl, rs, cs * 2, l0);
        ldst(xh, rs, cs * 2 + 1, h1); ldst(xl, rs, cs * 2 + 1, l1);
        ldst(bh_, rs, cs * 2, wc[0]); ldst(bh_, rs, cs * 2 + 1, wc[1]);
        ldst(bl_, rs, cs * 2, wc[2]); ldst(bl_, rs, cs * 2 + 1, wc[3]);
        if (kc + 64 < 1024) ldrow(kc + 64, xn, wn);   // prefetch next chunk
        __syncthreads();
        #pragma unroll
        for (int s = 0; s < 2; ++s) {
            bf16x8 ah = ldsf(xh, w * 16 + (lane & 15), s * 4 + (lane >> 4));
            bf16x8 al = ldsf(xl, w * 16 + (lane & 15), s * 4 + (lane >> 4));
            #pragma unroll
            for (int nt = 0; nt < 4; ++nt) {
                bf16x8 bh = ldsf(bh_, nt * 16 + (lane & 15), s * 4 + (lane >> 4));
                bf16x8 bl = ldsf(bl_, nt * 16 + (lane & 15), s * 4 + (lane >> 4));
                acc[nt] = MFMA16(ah, bh, acc[nt], 0, 0, 0);
                acc[nt] = MFMA16(ah, bl, acc[nt], 0, 0, 0);
                acc[nt] = MFMA16(al, bh, acc[nt], 0, 0, 0);
            }
        }
        #pragma unroll
        for (int i = 0; i < 4; ++i) { xc[i] = xn[i]; wc[i] = wn[i]; }
    }
    const float qs = (p == 0) ? 0.125f : 1.0f;          // fold 1/sqrt(64) into q
    #pragma unroll
    for (int nt = 0; nt < 4; ++nt)
        #pragma unroll
        for (int r = 0; r < 4; ++r) {
            float v = acc[nt][r] * qs;
            u16 hb = f2bf(v);
            u16 lb = f2bf(v - bf2f(hb));
            size_t idx = ((size_t)rt * 64 + w * 16 + (lane >> 4) * 4 + r) * 64 + nt * 16 + (lane & 15);
            oh[idx] = hb; ol[idx] = lb;
        }
}

// ---------------- V transpose: v[b][2048][64] -> vT[b][64][2048] (bf16 hi/lo) --
__global__ __launch_bounds__(256) void vt_kernel(char* __restrict__ ws) {
    const int st = blockIdx.x, b = blockIdx.y;          // st: 0..31
    __shared__ u16 lh[64 * 72], ll[64 * 72];
    const int t = threadIdx.x, row = t >> 2, cg = t & 3;
    const u16* vh = (const u16*)(ws + VHO) + ((size_t)b * 2048 + st * 64 + row) * 64 + cg * 16;
    const u16* vl = (const u16*)(ws + VLO) + ((size_t)b * 2048 + st * 64 + row) * 64 + cg * 16;
    *reinterpret_cast<uint4*>(&lh[row * 72 + cg * 16]) = *reinterpret_cast<const uint4*>(vh);
    *reinterpret_cast<uint4*>(&lh[row * 72 + cg * 16 + 8]) = *reinterpret_cast<const uint4*>(vh + 8);
    *reinterpret_cast<uint4*>(&ll[row * 72 + cg * 16]) = *reinterpret_cast<const uint4*>(vl);
    *reinterpret_cast<uint4*>(&ll[row * 72 + cg * 16 + 8]) = *reinterpret_cast<const uint4*>(vl + 8);
    __syncthreads();
    const int d = row, s0 = cg * 16;
    u32 wh[8], wl[8];
    #pragma unroll
    for (int j = 0; j < 8; ++j) {
        wh[j] = (u32)lh[(s0 + 2 * j) * 72 + d] | ((u32)lh[(s0 + 2 * j + 1) * 72 + d] << 16);
        wl[j] = (u32)ll[(s0 + 2 * j) * 72 + d] | ((u32)ll[(s0 + 2 * j + 1) * 72 + d] << 16);
    }
    u16* th = (u16*)(ws + VTH) + ((size_t)b * 64 + d) * 2048 + st * 64 + s0;
    u16* tl = (u16*)(ws + VTL) + ((size_t)b * 64 + d) * 2048 + st * 64 + s0;
    uint4 a = {wh[0], wh[1], wh[2], wh[3]}, bb = {wh[4], wh[5], wh[6], wh[7]};
    uint4 c = {wl[0], wl[1], wl[2], wl[3]}, dd = {wl[4], wl[5], wl[6], wl[7]};
    *reinterpret_cast<uint4*>(th) = a; *reinterpret_cast<uint4*>(th + 8) = bb;
    *reinterpret_cast<uint4*>(tl) = c; *reinterpret_cast<uint4*>(tl + 8) = dd;
}

// packed causal-chunk slot base: sum over j<qt of (j/4+1)
__device__ __forceinline__ int slot_base(int qt) {
    const int q4 = qt >> 2, r = qt & 3;
    return qt + 2 * q4 * (q4 - 1) + r * q4;
}

// ---------------- flash attention: split-bf16 MFMA + async-stage --------------
__global__ __launch_bounds__(256) void attn_kernel(char* __restrict__ ws) {
    const int chunk = blockIdx.x;            // 0..7
    const int qt = 31 - blockIdx.y;
    const int b = blockIdx.z;
    const int Li = qt + 1, kt0 = chunk * 4;
    if (kt0 >= Li) return;
    const int kt1 = (kt0 + 4 < Li) ? kt0 + 4 : Li;
    __shared__ char kh[8192], kl[8192], vh[8192], vl[8192], ph[8192], pl[8192];
    const int t = threadIdx.x, lane = t & 63, w = t >> 6;
    const int rs = t >> 2, cs = t & 3;
    // Q fragments straight from global (hi/lo), once
    const u16* qhg = (const u16*)(ws + QH);
    const u16* qlg = (const u16*)(ws + QL);
    const size_t qrow = (size_t)b * 2048 + qt * 64 + w * 16 + (lane & 15);
    bf16x8 qfh[2], qfl[2];
    #pragma unroll
    for (int s = 0; s < 2; ++s) {
        qfh[s] = *reinterpret_cast<const bf16x8*>(qhg + qrow * 64 + s * 32 + (lane >> 4) * 8);
        qfl[s] = *reinterpret_cast<const bf16x8*>(qlg + qrow * 64 + s * 32 + (lane >> 4) * 8);
    }
    const u16* kgh = (const u16*)(ws + KHO) + (size_t)b * 2048 * 64;
    const u16* kgl = (const u16*)(ws + KLO) + (size_t)b * 2048 * 64;
    const u16* vgh = (const u16*)(ws + VTH) + (size_t)b * 64 * 2048;
    const u16* vgl = (const u16*)(ws + VTL) + (size_t)b * 64 * 2048;

    auto ldreg = [&](int kt, bf16x8* r) {
        const u16* pk_h = kgh + (size_t)kt * 4096 + (size_t)rs * 64 + cs * 16;
        const u16* pk_l = kgl + (size_t)kt * 4096 + (size_t)rs * 64 + cs * 16;
        const u16* pv_h = vgh + (size_t)rs * 2048 + kt * 64 + cs * 16;
        const u16* pv_l = vgl + (size_t)rs * 2048 + kt * 64 + cs * 16;
        r[0] = *reinterpret_cast<const bf16x8*>(pk_h);
        r[1] = *reinterpret_cast<const bf16x8*>(pk_h + 8);
        r[2] = *reinterpret_cast<const bf16x8*>(pk_l);
        r[3] = *reinterpret_cast<const bf16x8*>(pk_l + 8);
        r[4] = *reinterpret_cast<const bf16x8*>(pv_h);
        r[5] = *reinterpret_cast<const bf16x8*>(pv_h + 8);
        r[6] = *reinterpret_cast<const bf16x8*>(pv_l);
        r[7] = *reinterpret_cast<const bf16x8*>(pv_l + 8);
    };
    auto stlds = [&](bf16x8* r) {
        ldst(kh, rs, cs * 2, r[0]); ldst(kh, rs, cs * 2 + 1, r[1]);
        ldst(kl, rs, cs * 2, r[2]); ldst(kl, rs, cs * 2 + 1, r[3]);
        ldst(vh, rs, cs * 2, r[4]); ldst(vh, rs, cs * 2 + 1, r[5]);
        ldst(vl, rs, cs * 2, r[6]); ldst(vl, rs, cs * 2 + 1, r[7]);
    };

    f32x4 o[4];
    #pragma unroll
    for (int nt = 0; nt < 4; ++nt) o[nt] = (f32x4){0.f, 0.f, 0.f, 0.f};
    float mrow[4], lrow[4];
    #pragma unroll
    for (int r = 0; r < 4; ++r) { mrow[r] = -1e30f; lrow[r] = 0.f; }

    bf16x8 rc[8], rn[8];
    ldreg(kt0, rc);
    for (int kt = kt0; kt < kt1; ++kt) {
        __syncthreads();              // prior iteration's LDS reads complete
        stlds(rc);
        if (kt + 1 < kt1) ldreg(kt + 1, rn);   // prefetch next K/V tile
        __syncthreads();              // staged tile visible
        f32x4 sacc[4];
        #pragma unroll
        for (int nt = 0; nt < 4; ++nt) sacc[nt] = (f32x4){0.f, 0.f, 0.f, 0.f};
        #pragma unroll
        for (int s = 0; s < 2; ++s) {
            #pragma unroll
            for (int nt = 0; nt < 4; ++nt) {
                bf16x8 bh = ldsf(kh, nt * 16 + (lane & 15), s * 4 + (lane >> 4));
                bf16x8 bl = ldsf(kl, nt * 16 + (lane & 15), s * 4 + (lane >> 4));
                sacc[nt] = MFMA16(qfh[s], bh, sacc[nt], 0, 0, 0);
                sacc[nt] = MFMA16(qfh[s], bl, sacc[nt], 0, 0, 0);
                sacc[nt] = MFMA16(qfl[s], bh, sacc[nt], 0, 0, 0);
            }
        }
        if (kt == qt) {   // diagonal tile causal mask (tile-local compare)
            #pragma unroll
            for (int nt = 0; nt < 4; ++nt)
                #pragma unroll
                for (int r = 0; r < 4; ++r)
                    if (nt * 16 + (lane & 15) > w * 16 + (lane >> 4) * 4 + r)
                        sacc[nt][r] = -1e30f;
        }
        // online softmax (rows r across regs; cols across 16-lane groups)
        float pcur[4][4], scv[4];
        #pragma unroll
        for (int r = 0; r < 4; ++r) {
            float mx = fmaxf(fmaxf(sacc[0][r], sacc[1][r]), fmaxf(sacc[2][r], sacc[3][r]));
            #pragma unroll
            for (int off = 1; off < 16; off <<= 1) mx = fmaxf(mx, __shfl_xor(mx, off));
            const float nm = fmaxf(mrow[r], mx);
            scv[r] = __expf(mrow[r] - nm);
            mrow[r] = nm;
            float rs_ = 0.f;
            #pragma unroll
            for (int nt = 0; nt < 4; ++nt) {
                float pv = __expf(sacc[nt][r] - nm);
                pcur[nt][r] = pv; rs_ += pv;
            }
            #pragma unroll
            for (int off = 1; off < 16; off <<= 1) rs_ += __shfl_xor(rs_, off);
            lrow[r] = lrow[r] * scv[r] + rs_;
        }
        f32x4 scq = {scv[0], scv[1], scv[2], scv[3]};
        #pragma unroll
        for (int nt = 0; nt < 4; ++nt) o[nt] *= scq;
        // split P and write to per-wave LDS region (rows w*16..w*16+15)
        #pragma unroll
        for (int nt = 0; nt < 4; ++nt)
            #pragma unroll
            for (int r = 0; r < 4; ++r) {
                const int row = w * 16 + (lane >> 4) * 4 + r;
                const int key = nt * 16 + (lane & 15);
                u16 hb = f2bf(pcur[nt][r]);
                u16 lb = f2bf(pcur[nt][r] - bf2f(hb));
                const int byt = row * 128 + swz(row, key >> 3) * 16 + (key & 7) * 2;
                *reinterpret_cast<u16*>(ph + byt) = hb;
                *reinterpret_cast<u16*>(pl + byt) = lb;
            }
        // PV (wave-local P readback; compiler orders same-wave ds ops)
        #pragma unroll
        for (int s = 0; s < 2; ++s) {
            bf16x8 pah = ldsf(ph, w * 16 + (lane & 15), s * 4 + (lane >> 4));
            bf16x8 pal = ldsf(pl, w * 16 + (lane & 15), s * 4 + (lane >> 4));
            #pragma unroll
            for (int nt = 0; nt < 4; ++nt) {
                bf16x8 vbh = ldsf(vh, nt * 16 + (lane & 15), s * 4 + (lane >> 4));
                bf16x8 vbl = ldsf(vl, nt * 16 + (lane & 15), s * 4 + (lane >> 4));
                o[nt] = MFMA16(pah, vbh, o[nt], 0, 0, 0);
                o[nt] = MFMA16(pah, vbl, o[nt], 0, 0, 0);
                o[nt] = MFMA16(pal, vbh, o[nt], 0, 0, 0);
            }
        }
        #pragma unroll
        for (int i = 0; i < 8; ++i) rc[i] = rn[i];
    }
    const int slot = b * 144 + slot_base(qt) + chunk;
    float* Op = (float*)(ws + OPOFF) + (size_t)slot * 4096;
    #pragma unroll
    for (int nt = 0; nt < 4; ++nt)
        #pragma unroll
        for (int r = 0; r < 4; ++r)
            Op[(size_t)(w * 16 + (lane >> 4) * 4 + r) * 64 + nt * 16 + (lane & 15)] = o[nt][r];
    if ((lane & 15) == 0) {
        float* Pm = (float*)(ws + PMOFF);
        float* Pl = (float*)(ws + PLOFF);
        #pragma unroll
        for (int r = 0; r < 4; ++r) {
            Pm[(size_t)slot * 64 + w * 16 + (lane >> 4) * 4 + r] = mrow[r];
            Pl[(size_t)slot * 64 + w * 16 + (lane >> 4) * 4 + r] = lrow[r];
        }
    }
}

// ---------------- merge partials -> final output (one elem per thread) --------
__global__ __launch_bounds__(256) void merge_kernel(const char* __restrict__ ws,
                                                    float* __restrict__ out) {
    // grid: x = qt*16 + rb, y = b ; block = 4 rows x 64 dims
    const int qt = blockIdx.x >> 4, rb = blockIdx.x & 15, b = blockIdx.y;
    const int t = threadIdx.x, d = t & 63, rloc = t >> 6;
    const int row = rb * 4 + rloc;
    const int Ci = (qt >> 2) + 1;
    const int slot0 = b * 144 + slot_base(qt);
    const float* Op = (const float*)(ws + OPOFF);
    const float* Pm = (const float*)(ws + PMOFF);
    const float* Pl = (const float*)(ws + PLOFF);
    float M = -1e30f;
    for (int c = 0; c < Ci; ++c) M = fmaxf(M, Pm[(size_t)(slot0 + c) * 64 + row]);
    float den = 0.f, acc = 0.f;
    for (int c = 0; c < Ci; ++c) {
        const float wv = __expf(Pm[(size_t)(slot0 + c) * 64 + row] - M);
        den += wv * Pl[(size_t)(slot0 + c) * 64 + row];
        acc += wv * Op[(size_t)(slot0 + c) * 4096 + (size_t)row * 64 + d];
    }
    out[(size_t)((b * 32 + qt) * 64 + row) * 64 + d] = acc / den;
}

extern "C" void kernel_launch(void* const* d_in, const int* in_sizes, int n_in,
                              void* d_out, int out_size, void* d_ws, size_t ws_size,
                              hipStream_t stream) {
    (void)in_sizes; (void)n_in; (void)out_size; (void)ws_size;
    const float* Q  = (const float*)d_in[0];
    const float* K  = (const float*)d_in[1];
    const float* V  = (const float*)d_in[2];
    const float* WQ = (const float*)d_in[3];
    const float* WK = (const float*)d_in[4];
    const float* WV = (const float*)d_in[5];
    char* ws   = (char*)d_ws;
    float* out = (float*)d_out;

    wsplit_kernel<<<dim3(16, 3), dim3(256), 0, stream>>>(WQ, WK, WV, ws);
    proj_kernel<<<dim3(128, 3), dim3(256), 0, stream>>>(Q, K, V, ws);
    vt_kernel<<<dim3(32, 4), dim3(256), 0, stream>>>(ws);
    attn_kernel<<<dim3(8, 32, 4), dim3(256), 0, stream>>>(ws);
    merge_kernel<<<dim3(512, 4), dim3(256), 0, stream>>>(ws, out);
}